// Round 5
// baseline (422.618 us; speedup 1.0000x reference)
//
#include <hip/hip_runtime.h>
#include <hip/hip_cooperative_groups.h>

namespace cg = cooperative_groups;

#define BATCH 16
#define T_LEN 2048
#define E_DIM 768
#define E4 (E_DIM / 4)        // 192 float4 per row
#define N_SENT 32
#define S_LEN 64
#define NCHUNK 64             // T chunks of 32 rows; grid = BATCH*NCHUNK = 1024
#define RPC (T_LEN / NCHUNK)  // 32 rows per chunk

typedef float v4f __attribute__((ext_vector_type(4)));

// One cooperative kernel: pool -> grid.sync -> idx -> grid.sync -> gather.
// 1024 blocks x 256 threads = 4 blocks/CU (co-resident for grid sync).
__global__ void __launch_bounds__(256, 4)
fused(const v4f* __restrict__ in4,
      const float* __restrict__ W,
      const float* __restrict__ bias,
      v4f* __restrict__ partial4,
      int* __restrict__ sidx, int* __restrict__ eidx,
      v4f* __restrict__ out4) {
    cg::grid_group grid = cg::this_grid();
    const int tid = threadIdx.x;

    // ---- Phase 1: partial column sums. block = (b, tc); 192 active lanes ----
    {
        const int b  = blockIdx.x >> 6;          // /NCHUNK
        const int tc = blockIdx.x & (NCHUNK - 1);
        if (tid < E4) {
            const v4f* p = in4 + ((size_t)b * T_LEN + (size_t)tc * RPC) * E4 + tid;
            v4f s = (v4f){0.f, 0.f, 0.f, 0.f};
#pragma unroll 8
            for (int t = 0; t < RPC; ++t) s += p[(size_t)t * E4];
            partial4[((size_t)tc * BATCH + b) * E4 + tid] = s;
        }
    }
    grid.sync();

    // ---- Phase 2: finish mean + tiny matmul + index computation (blocks 0..15) ----
    if (blockIdx.x < BATCH) {
        __shared__ float pooled[E_DIM];
        __shared__ float colsum[4][2 * N_SENT];
        __shared__ int   offi[2 * N_SENT];
        const int b = blockIdx.x;

        if (tid < E4) {
            v4f s = (v4f){0.f, 0.f, 0.f, 0.f};
#pragma unroll 8
            for (int tc = 0; tc < NCHUNK; ++tc)
                s += partial4[((size_t)tc * BATCH + b) * E4 + tid];
            const float inv = 1.0f / (float)T_LEN;
            ((v4f*)pooled)[tid] = s * inv;
        }
        __syncthreads();

        // tid -> (quarter q, column c): pooled reads broadcast, W reads coalesced.
        const int c = tid & 63;
        const int q = tid >> 6;
        float acc = 0.f;
        const float* pb = pooled + q * 192;
        const float* Wq = W + (size_t)q * 192 * (2 * N_SENT) + c;
#pragma unroll 8
        for (int e = 0; e < 192; ++e) acc += pb[e] * Wq[(size_t)e * (2 * N_SENT)];
        colsum[q][c] = acc;
        __syncthreads();

        if (tid < 2 * N_SENT) {
            float o = bias[tid] + colsum[0][tid] + colsum[1][tid] + colsum[2][tid] + colsum[3][tid];
            // clip to [0, 63] then truncate (nonneg -> floor), matching astype(int32)
            float cl = fminf(fmaxf(o, 0.f), (float)(S_LEN - 1));
            offi[tid] = (int)cl;
        }
        __syncthreads();

        if (tid < N_SENT) {
            const int so   = offi[tid];
            const int eo   = offi[N_SENT + tid];
            const int base = tid * S_LEN;
            int si = min(base + so, T_LEN - S_LEN);            // clip(base+so, 0, T-L)
            int ei = min(max(base + S_LEN + eo, si), T_LEN);   // clip(base+L+eo, si, T)
            sidx[b * N_SENT + tid] = si;
            eidx[b * N_SENT + tid] = ei;
        }
    }
    grid.sync();

    // ---- Phase 3: gather 32 rows per block (wave handles 8 rows x 3 segments) ----
    {
        const int wave = tid >> 6;
        const int lane = tid & 63;
        const int row0 = blockIdx.x * 32 + wave * 8;
#pragma unroll
        for (int r = 0; r < 8; ++r) {
            const int row = row0 + r;               // b*S*L + s*L + j
            const int j = row & (S_LEN - 1);
            const int s = (row >> 6) & (N_SENT - 1);
            const int b = row >> 11;
            const int si = sidx[b * N_SENT + s];
            const int ei = eidx[b * N_SENT + s];
            const bool valid = j < (ei - si);
            const v4f* src = in4 + ((size_t)b * T_LEN + (si + j)) * E4 + lane;
            v4f* dst = out4 + (size_t)row * E4 + lane;
#pragma unroll
            for (int seg = 0; seg < 3; ++seg) {
                v4f v = (v4f){0.f, 0.f, 0.f, 0.f};
                if (valid) v = src[seg * 64];
                dst[seg * 64] = v;                  // always write (out is poisoned)
            }
        }
    }
}

extern "C" void kernel_launch(void* const* d_in, const int* in_sizes, int n_in,
                              void* d_out, int out_size, void* d_ws, size_t ws_size,
                              hipStream_t stream) {
    const v4f*   in4  = (const v4f*)d_in[0];   // [16, 2048, 768]
    const float* W    = (const float*)d_in[1]; // [768, 64]
    const float* bias = (const float*)d_in[2]; // [64]
    v4f* out4 = (v4f*)d_out;                   // [16, 32, 64, 768]

    v4f* partial4 = (v4f*)d_ws;                // NCHUNK*BATCH*E4 v4f = 3 MB
    int* sidx = (int*)((char*)d_ws + (size_t)NCHUNK * BATCH * E4 * sizeof(v4f));
    int* eidx = sidx + BATCH * N_SENT;

    void* args[] = {(void*)&in4, (void*)&W, (void*)&bias,
                    (void*)&partial4, (void*)&sidx, (void*)&eidx, (void*)&out4};
    hipLaunchCooperativeKernel((const void*)fused, dim3(BATCH * NCHUNK), dim3(256),
                               args, 0, stream);
}